// Round 5
// baseline (125.080 us; speedup 1.0000x reference)
//
#include <hip/hip_runtime.h>
#include <math.h>

// Problem constants (from reference)
#define BB 64
#define TT 100
#define NN 20
#define NRR 380   // N*(N-1)

typedef float f32x4 __attribute__((ext_vector_type(4)));

__device__ __forceinline__ void compute_row(
    int r, float ri0, float ri1, float ri2,
    const float* __restrict__ s_state, const float* __restrict__ s_shape,
    float4* __restrict__ s_row4, float* __restrict__ s_mask, int* __restrict__ s_ij)
{
    const float THRESH  = 0.35f;
    const float HALF_PI = 1.57079632679489661923f; // float32(pi/2)

    const int i = r / 19;
    const int l = r - i * 19;
    const int j = (l < i) ? l : (l + 1);

    const float* si = &s_state[i * 8];
    const float* sj = &s_state[j * 8];

    const float dx = si[0] - sj[0];
    const float dy = si[1] - sj[1];
    const float d  = sqrtf(dx * dx + dy * dy);
    const float mask = (d < THRESH && d > 0.0f) ? 1.0f : 0.0f;

    const float dpx   = mask * (sj[0] - si[0]);
    const float dpy   = mask * (sj[1] - si[1]);
    const float adiff = mask * (sj[2] - si[2]);
    const float dvx   = mask * (sj[3] - si[3]);
    const float dvy   = mask * (sj[4] - si[4]);
    const float adv   = mask * (sj[5] - si[5]);
    const float cx    = mask * sj[6];
    const float cy    = mask * sj[7];

    const float rang = mask * si[2];
    const float c1 = cosf(rang),           s1 = sinf(rang);
    const float c2 = cosf(rang + HALF_PI), s2 = sinf(rang + HALF_PI);

    float4 w0, w1, w2, w3, w4;
    w0.x = ri0; w0.y = ri1; w0.z = ri2;
    w0.w = c1 * dpx + s1 * dpy;
    w1.x = c2 * dpx + s2 * dpy;
    w1.y = c1 * dvx + s1 * dvy;
    w1.z = c2 * dvx + s2 * dvy;
    w1.w = c1 * cx  + s1 * cy;
    w2.x = c2 * cx  + s2 * cy;
    w2.y = sinf(2.0f * adiff);
    w2.z = cosf(2.0f * adiff);   // == 1 when masked out, as in reference
    w2.w = adv;
    w3.x = mask * s_shape[i * 4 + 0];
    w3.y = mask * s_shape[i * 4 + 1];
    w3.z = mask * s_shape[i * 4 + 2];
    w3.w = mask * s_shape[i * 4 + 3];
    w4.x = mask * s_shape[j * 4 + 0];
    w4.y = mask * s_shape[j * 4 + 1];
    w4.z = mask * s_shape[j * 4 + 2];
    w4.w = mask * s_shape[j * 4 + 3];

    float4* row = &s_row4[r * 5];
    row[0] = w0; row[1] = w1; row[2] = w2; row[3] = w3; row[4] = w4;
    s_mask[r] = mask;
    s_ij[r]   = i | (j << 8);
}

__global__ __launch_bounds__(256) void gp_kernel(
    const float* __restrict__ state,    // (B,T,N,8)
    const float* __restrict__ shape,    // (B,T,N,4)
    const float* __restrict__ relinfo,  // (B,T,NR,3)
    float* __restrict__ out)
{
    const int bt  = blockIdx.x;       // 0..B*T-1
    const int tid = threadIdx.x;

    __shared__ float  s_state[NN * 8];     // 160 floats
    __shared__ float  s_shape[NN * 4];     // 80 floats
    __shared__ float4 s_row4[NRR * 5];     // full rel_data rows, output-linear (30.4 KB)
    __shared__ float  s_mask[NRR];
    __shared__ int    s_ij[NRR];

    // ---- phase 0: stage state/shape; pre-issue this thread's relinfo into regs ----
    // row1 = tid (always < 380); row2 = tid+256 (valid iff tid < 124, else clamp)
    const int   r2v   = tid + 256;
    const int   r2c   = (r2v < NRR) ? r2v : (NRR - 1);
    const float* rbase = relinfo + (size_t)bt * NRR * 3;
    const float ra0 = rbase[tid * 3 + 0];
    const float ra1 = rbase[tid * 3 + 1];
    const float ra2 = rbase[tid * 3 + 2];
    const float rb0 = rbase[r2c * 3 + 0];
    const float rb1 = rbase[r2c * 3 + 1];
    const float rb2 = rbase[r2c * 3 + 2];

    if (tid < NN * 8)                   s_state[tid]          = state[(size_t)bt * NN * 8 + tid];
    else if (tid < NN * 8 + NN * 4)     s_shape[tid - NN * 8] = shape[(size_t)bt * NN * 4 + (tid - NN * 8)];
    __syncthreads();

    const size_t REL_SZ = (size_t)BB * TT * NRR * 20;
    const size_t OBJ_SZ = (size_t)BB * TT * NN * 7;
    f32x4* relb  = (f32x4*)out                              + (size_t)bt * (NRR * 5);
    float* objb  = out + REL_SZ                             + (size_t)bt * (NN * 7);
    f32x4* recvb = (f32x4*)(out + REL_SZ + OBJ_SZ)          + (size_t)bt * (NRR * 5);
    f32x4* sendb = (f32x4*)(out + REL_SZ + OBJ_SZ + REL_SZ) + (size_t)bt * (NRR * 5);

    // ---- obj_data: 140 consecutive floats per bt ----
    if (tid < NN * 7) {
        const float HALF_PI = 1.57079632679489661923f;
        const int n = tid / 7;
        const int c = tid - n * 7;
        float v;
        if (c < 2) {
            const float ang = s_state[n * 8 + 2];
            const float a   = (c == 0) ? ang : (ang + HALF_PI);
            v = cosf(a) * s_state[n * 8 + 3] + sinf(a) * s_state[n * 8 + 4];
        } else if (c == 2) {
            v = s_state[n * 8 + 5];
        } else {
            v = s_shape[n * 4 + (c - 3)];
        }
        objb[tid] = v;
    }

    // ---- phase 1: each rel row computed ONCE into LDS ----
    compute_row(tid, ra0, ra1, ra2, s_state, s_shape, s_row4, s_mask, s_ij);
    if (r2v < NRR)
        compute_row(r2v, rb0, rb1, rb2, s_state, s_shape, s_row4, s_mask, s_ij);
    __syncthreads();

    // ---- phase 2: uniform 8-iter predicated blast, reads batched up front ----
    float4 w[8];
    float  m[8];
    int    ij[8];
#pragma unroll
    for (int k = 0; k < 8; ++k) {
        const int idx  = tid + k * 256;
        const int idxc = (idx < NRR * 5) ? idx : 0;
        w[k]  = s_row4[idxc];
        m[k]  = s_mask[idxc / 5];
        ij[k] = s_ij[idxc / 5];
    }
#pragma unroll
    for (int k = 0; k < 8; ++k) {
        const int idx = tid + k * 256;
        if (idx < NRR * 5) {
            const int r  = idx / 5;
            const int qb = (idx - r * 5) * 4;
            const int i  = ij[k] & 255;
            const int j  = ij[k] >> 8;
            f32x4 wv, rv, sv;
            wv.x = w[k].x; wv.y = w[k].y; wv.z = w[k].z; wv.w = w[k].w;
            rv.x = (i == qb + 0) ? m[k] : 0.0f;
            rv.y = (i == qb + 1) ? m[k] : 0.0f;
            rv.z = (i == qb + 2) ? m[k] : 0.0f;
            rv.w = (i == qb + 3) ? m[k] : 0.0f;
            sv.x = (j == qb + 0) ? m[k] : 0.0f;
            sv.y = (j == qb + 1) ? m[k] : 0.0f;
            sv.z = (j == qb + 2) ? m[k] : 0.0f;
            sv.w = (j == qb + 3) ? m[k] : 0.0f;
            __builtin_nontemporal_store(wv, &relb[idx]);
            __builtin_nontemporal_store(rv, &recvb[idx]);
            __builtin_nontemporal_store(sv, &sendb[idx]);
        }
    }
}

extern "C" void kernel_launch(void* const* d_in, const int* in_sizes, int n_in,
                              void* d_out, int out_size, void* d_ws, size_t ws_size,
                              hipStream_t stream) {
    const float* state = (const float*)d_in[0];
    const float* shp   = (const float*)d_in[1];
    const float* rel   = (const float*)d_in[2];
    float* out = (float*)d_out;
    gp_kernel<<<dim3(BB * TT), dim3(256), 0, stream>>>(state, shp, rel, out);
}